// Round 4
// baseline (494.194 us; speedup 1.0000x reference)
//
#include <hip/hip_runtime.h>
#include <math.h>

#define S_DIM 1024
#define B_DIM 4
#define E_DIM 1024
#define H_DIM 16
#define M_DIM 128
#define V_DIM 64

typedef __attribute__((ext_vector_type(8))) short short8;
typedef __attribute__((ext_vector_type(4))) float f32x4;
typedef __attribute__((ext_vector_type(16))) float f32x16;
typedef __attribute__((ext_vector_type(4))) int int4v;

__device__ __forceinline__ unsigned short f2bf(float f) {
    union { float f; unsigned u; } v; v.f = f;
    unsigned r = v.u + 0x7FFFu + ((v.u >> 16) & 1u);   // round-to-nearest-even
    return (unsigned short)(r >> 16);
}

__device__ __forceinline__ void async16(const unsigned short* g, unsigned short* l) {
    __builtin_amdgcn_global_load_lds(
        (const __attribute__((address_space(1))) void*)g,
        (__attribute__((address_space(3))) void*)l,
        16, 0, 0);
}

// ---------------- convert: fp32 (re,im) -> bf16, all 4 tensors in one launch ----------------
// segments (in float4 units): x 1048576 | wq 524288 | wk 524288 | wv 262144
__global__ __launch_bounds__(256) void convert_all(
    const float* __restrict__ xre,  const float* __restrict__ xim,
    const float* __restrict__ wqre, const float* __restrict__ wqim,
    const float* __restrict__ wkre, const float* __restrict__ wkim,
    const float* __restrict__ wvre, const float* __restrict__ wvim,
    unsigned short* __restrict__ xbre, unsigned short* __restrict__ xbim,
    unsigned short* __restrict__ wbre, unsigned short* __restrict__ wbim)
{
    const int i = blockIdx.x * 256 + threadIdx.x;
    const float *re, *im;
    unsigned short *dr, *di;
    int j;
    if (i < 1048576)      { re = xre;  im = xim;  dr = xbre;               di = xbim;               j = i; }
    else if (i < 1572864) { re = wqre; im = wqim; dr = wbre;               di = wbim;               j = i - 1048576; }
    else if (i < 2097152) { re = wkre; im = wkim; dr = wbre + 2048 * 1024; di = wbim + 2048 * 1024; j = i - 1572864; }
    else                  { re = wvre; im = wvim; dr = wbre + 4096 * 1024; di = wbim + 4096 * 1024; j = i - 2097152; }
    float4 r = ((const float4*)re)[j];
    float4 m = ((const float4*)im)[j];
    ushort4 ro, mo;
    ro.x = f2bf(r.x); ro.y = f2bf(r.y); ro.z = f2bf(r.z); ro.w = f2bf(r.w);
    mo.x = f2bf(m.x); mo.y = f2bf(m.y); mo.z = f2bf(m.z); mo.w = f2bf(m.w);
    ((ushort4*)dr)[j] = ro;
    ((ushort4*)di)[j] = mo;
}

// wo (e,f) -> woT (f,e) bf16
__global__ __launch_bounds__(256) void transpose_wo(
    const float* __restrict__ wore, const float* __restrict__ woim,
    unsigned short* __restrict__ wtre, unsigned short* __restrict__ wtim)
{
    __shared__ float tr[32][33], ti[32][33];
    const int bx = blockIdx.x * 32;   // e range
    const int by = blockIdx.y * 32;   // f range
    const int tx = threadIdx.x & 31, ty = threadIdx.x >> 5;
    for (int i = ty; i < 32; i += 8) {
        tr[i][tx] = wore[(bx + i) * E_DIM + by + tx];
        ti[i][tx] = woim[(bx + i) * E_DIM + by + tx];
    }
    __syncthreads();
    for (int i = ty; i < 32; i += 8) {
        wtre[(by + i) * E_DIM + bx + tx] = f2bf(tr[tx][i]);
        wtim[(by + i) * E_DIM + bx + tx] = f2bf(ti[tx][i]);
    }
}

// v planes [bh][t][64] -> v^T planes [bh][v][1024]
__global__ __launch_bounds__(256) void vtrans(
    const unsigned short* __restrict__ vrp, const unsigned short* __restrict__ vip,
    unsigned short* __restrict__ vrt, unsigned short* __restrict__ vit)
{
    __shared__ unsigned short tl[2][64][66];
    const int tid = threadIdx.x;
    const int t0 = blockIdx.x * 64;
    const int bh = blockIdx.y;
    #pragma unroll
    for (int pl = 0; pl < 2; ++pl) {
        const unsigned short* src = pl ? vip : vrp;
        #pragma unroll
        for (int p = 0; p < 2; ++p) {
            const int row = p * 32 + (tid >> 3);
            const int col = (tid & 7) * 8;
            short8 d = *(const short8*)&src[((size_t)bh * S_DIM + t0 + row) * V_DIM + col];
            #pragma unroll
            for (int j = 0; j < 8; ++j) tl[pl][row][col + j] = (unsigned short)d[j];
        }
    }
    __syncthreads();
    #pragma unroll
    for (int pl = 0; pl < 2; ++pl) {
        unsigned short* dst = pl ? vit : vrt;
        #pragma unroll
        for (int p = 0; p < 2; ++p) {
            const int v = p * 32 + (tid >> 3);
            const int tc = (tid & 7) * 8;
            short8 d;
            #pragma unroll
            for (int j = 0; j < 8; ++j) d[j] = (short)tl[pl][tc + j][v];
            *(short8*)&dst[((size_t)bh * V_DIM + v) * S_DIM + t0 + tc] = d;
        }
    }
}

// ---------------- complex bf16 MFMA GEMM: C = A * B^T (32x32x16 shape) ----------------
// Round-3 diagnosis: 16x16x32 at 128x64 tile is LDS-bandwidth co-limited
// (per block-slice: MFMA 621 cyc vs LDS ~658 cyc at 112 B/cyc/CU -> serialized
// pitch ~1275 cyc observed). Fix: 32x32x16 shape doubles FLOP per LDS byte
// (16B+16B frags -> 32768 FLOP) and runs 20% faster per FLOP (2382 vs 2075 TF).
// Geometry: block 128x128, 4 waves (2x2), wave tile 64x64, BK=32.
// 2-buffer T3-min double-buffer (64 KB LDS -> 2 blocks/CU): next slice's
// global_load_lds issued BEFORE current slice's ds_read+MFMA; vmcnt(0) after
// the MFMA cluster; one barrier per slice.
// Chunk-XOR swizzle (verified conflict-free in-harness): physical 16B chunk =
// logical ^ ((row>>1)&3); pre-swizzled GLOBAL source col (gload_lds dest
// stays linear) + same XOR on ds_read. 32-lane read phases land 2 lanes per
// bank-group -> conflict-free (same analysis as the verified 16x16 pattern).
// Frag layouts: A/B row = lane&31, k = (lane>>5)*8 + j;
// C/D col = lane&31, row = (reg&3) + 8*(reg>>2) + 4*(lane>>5)  [m74/m101].
// MODE 0: Mr=4096 (s,b), Nc=5120 (q|k|v) -> bf16 planes qr/qi/kr/ki/vr/vi
// MODE 1: Mr=4096, Nc=1024 -> out = acc + x (fp32, stacked re/im), plain stores
template<int MODE>
__global__ __launch_bounds__(256, 2) void cgemm(
    const unsigned short* __restrict__ Are, const unsigned short* __restrict__ Aim,
    const unsigned short* __restrict__ Bre, const unsigned short* __restrict__ Bim,
    unsigned short* __restrict__ qrp, unsigned short* __restrict__ qip,
    unsigned short* __restrict__ krp, unsigned short* __restrict__ kip,
    unsigned short* __restrict__ vrp, unsigned short* __restrict__ vip,
    const float* __restrict__ xre, const float* __restrict__ xim,
    float* __restrict__ out)
{
    // 64 KB: 2 slice buffers x (Ar[128][32] | Ai[128][32] | Br[128][32] | Bi[128][32])
    __shared__ __align__(16) unsigned short lds[32768];
    const int tid  = threadIdx.x;
    const int wave = tid >> 6;
    const int lane = tid & 63;
    const int r0 = blockIdx.x * 128;   // m fastest: consecutive blocks share B panel
    const int j0 = blockIdx.y * 128;
    const int wm = (wave >> 1) * 64;   // m half
    const int wn = (wave & 1) * 64;    // n half

    f32x16 accre[2][2], accim[2][2];
    #pragma unroll
    for (int i = 0; i < 2; ++i)
        #pragma unroll
        for (int j = 0; j < 2; ++j) {
            #pragma unroll
            for (int e = 0; e < 16; ++e) { accre[i][j][e] = 0.f; accim[i][j][e] = 0.f; }
        }

    // staging: thread t covers rows sr=t>>2 and sr+64 of each plane, physical
    // 16B chunk t&3. Physical chunk holds logical chunk (t&3)^((row>>1)&3);
    // since gload_lds dest must stay linear, XOR is applied to the GLOBAL col.
    const int sr   = tid >> 2;
    const int sc   = (tid & 3) * 8;                          // physical chunk (shorts)
    const int scol = ((tid & 3) ^ ((tid >> 3) & 3)) * 8;     // pre-swizzled source col

    const int l31 = lane & 31;                               // frag row index
    const int l5  = lane >> 5;                               // k-half select
    const int lxk = (lane >> 1) & 3;                         // swizzle key ((row>>1)&3)

    #define STAGE(sl, bb) { \
        const int kg = (sl) * 32; \
        unsigned short* b_ = &lds[(bb) * 16384]; \
        const size_t ga0 = (size_t)(r0 + sr) * E_DIM + kg + scol; \
        const size_t ga1 = (size_t)(r0 + 64 + sr) * E_DIM + kg + scol; \
        const size_t gb0 = (size_t)(j0 + sr) * E_DIM + kg + scol; \
        const size_t gb1 = (size_t)(j0 + 64 + sr) * E_DIM + kg + scol; \
        async16(Are + ga0, b_ + sr * 32 + sc); \
        async16(Are + ga1, b_ + (64 + sr) * 32 + sc); \
        async16(Aim + ga0, b_ + 4096 + sr * 32 + sc); \
        async16(Aim + ga1, b_ + 4096 + (64 + sr) * 32 + sc); \
        async16(Bre + gb0, b_ + 8192 + sr * 32 + sc); \
        async16(Bre + gb1, b_ + 8192 + (64 + sr) * 32 + sc); \
        async16(Bim + gb0, b_ + 12288 + sr * 32 + sc); \
        async16(Bim + gb1, b_ + 12288 + (64 + sr) * 32 + sc); }

    // prologue: slice 0 -> buf0, drain, barrier
    STAGE(0, 0)
    asm volatile("s_waitcnt vmcnt(0)" ::: "memory");
    __builtin_amdgcn_s_barrier();

    #pragma unroll 1
    for (int s = 0; s < 32; ++s) {
        // issue next slice's loads first (fly during ds_read + MFMA below)
        if (s < 31) STAGE(s + 1, (s + 1) & 1)

        const unsigned short* buf = &lds[(s & 1) * 16384];

        #pragma unroll
        for (int kk = 0; kk < 2; ++kk) {
            const int ck = ((kk * 2 + l5) ^ lxk) * 8;   // swizzled chunk offset (shorts)
            short8 ar[2], ai[2], br[2], bi[2];
            #pragma unroll
            for (int mt = 0; mt < 2; ++mt) {
                const int ro = (wm + mt * 32 + l31) * 32 + ck;
                ar[mt] = *(const short8*)&buf[ro];
                ai[mt] = *(const short8*)&buf[4096 + ro];
            }
            #pragma unroll
            for (int nt = 0; nt < 2; ++nt) {
                const int ro = (wn + nt * 32 + l31) * 32 + ck;
                br[nt] = *(const short8*)&buf[8192 + ro];
                bi[nt] = *(const short8*)&buf[12288 + ro];
            }
            #pragma unroll
            for (int nt = 0; nt < 2; ++nt) {
                int4v t = *(int4v*)&bi[nt];
                t = t ^ (int)0x80008000;       // bin = -bi (transient)
                const short8 bin = *(short8*)&t;
                #pragma unroll
                for (int mt = 0; mt < 2; ++mt) {
                    accre[mt][nt] = __builtin_amdgcn_mfma_f32_32x32x16_bf16(ar[mt], br[nt], accre[mt][nt], 0, 0, 0);
                    accre[mt][nt] = __builtin_amdgcn_mfma_f32_32x32x16_bf16(ai[mt], bin,    accre[mt][nt], 0, 0, 0);
                    accim[mt][nt] = __builtin_amdgcn_mfma_f32_32x32x16_bf16(ar[mt], bi[nt], accim[mt][nt], 0, 0, 0);
                    accim[mt][nt] = __builtin_amdgcn_mfma_f32_32x32x16_bf16(ai[mt], br[nt], accim[mt][nt], 0, 0, 0);
                }
            }
        }

        if (s < 31) {
            // next slice fully landed (loads had the whole MFMA cluster to fly);
            // all waves' ds_reads of buf[s&1] retired (consumed by MFMA) ->
            // after this barrier buf[s&1] is safe to overwrite at s+1.
            asm volatile("s_waitcnt vmcnt(0)" ::: "memory");
            __builtin_amdgcn_s_barrier();
        }
    }
    #undef STAGE

    // epilogue: D col = lane&31, row = (reg&3) + 8*(reg>>2) + 4*(lane>>5)
    #pragma unroll
    for (int mt = 0; mt < 2; ++mt) {
        #pragma unroll
        for (int nt = 0; nt < 2; ++nt) {
            #pragma unroll
            for (int reg = 0; reg < 16; ++reg) {
                const int r = r0 + wm + mt * 32 + (reg & 3) + 8 * (reg >> 2) + 4 * l5;
                const int j = j0 + wn + nt * 32 + l31;
                const float vr = accre[mt][nt][reg];
                const float vi = accim[mt][nt][reg];
                if (MODE == 0) {
                    const int s = r >> 2, b = r & 3;   // r = s*B + b
                    if (j < 2048) {
                        const int h = j >> 7, m = j & 127;
                        const size_t off = ((size_t)(b * H_DIM + h) * S_DIM + s) * M_DIM + m;
                        qrp[off] = f2bf(vr); qip[off] = f2bf(vi);
                    } else if (j < 4096) {
                        const int jl = j - 2048, h = jl >> 7, m = jl & 127;
                        const size_t off = ((size_t)(b * H_DIM + h) * S_DIM + s) * M_DIM + m;
                        krp[off] = f2bf(vr); kip[off] = f2bf(vi);
                    } else {
                        const int jl = j - 4096, h = jl >> 6, vv = jl & 63;
                        const size_t off = ((size_t)(b * H_DIM + h) * S_DIM + s) * V_DIM + vv;
                        vrp[off] = f2bf(vr); vip[off] = f2bf(vi);
                    }
                } else {
                    const int idx = r * E_DIM + j;
                    out[idx] = vr + xre[idx];
                    out[S_DIM * B_DIM * E_DIM + idx] = vi + xim[idx];
                }
            }
        }
    }
}

// ---------------- K2: MFMA flash attention, S^T orientation ----------------
// block = one (b,h) x 64 q; 4 waves x 16 q-cols; K-tile 64.
// S^T = K*Q^T: C col = q = lane&15 -> t-reduction is in-lane + 2 quad shfls;
// m/l/alpha are per-lane scalars. O accumulates as O^T[v][q] (col=q).
// setprio(1) around MFMA clusters (T5: +4-7% on attn, m191).
__global__ __launch_bounds__(256, 2) void attn_mfma(
    const unsigned short* __restrict__ qr, const unsigned short* __restrict__ qi,
    const unsigned short* __restrict__ kr, const unsigned short* __restrict__ ki,
    const unsigned short* __restrict__ vrt, const unsigned short* __restrict__ vit,
    unsigned short* __restrict__ updre, unsigned short* __restrict__ updim)
{
    __shared__ __align__(16) unsigned short Ks[2][64][136];  // K tile [plane][t][m] (Q staged here first)
    __shared__ __align__(16) unsigned short Vs[2][64][72];   // V^T tile [plane][v][t]
    __shared__ __align__(16) unsigned short Ps[4][16][80];   // per-wave P [q][t], pitch 80: 2-way banks

    const int tid  = threadIdx.x;
    const int wave = tid >> 6;
    const int lane = tid & 63;
    const int qt = (int)gridDim.x - 1 - blockIdx.x;  // long blocks launch first
    const int bh = blockIdx.y;
    const int q0 = qt * 64;
    const size_t base_qk = (size_t)bh * S_DIM * M_DIM;
    const size_t base_v  = (size_t)bh * V_DIM * S_DIM;

    const int fr = lane & 15;        // q col (QK/PV); A-frag row index
    const int fg = lane >> 4;        // quad 0..3
    const int fk = fg * 8;           // frag k offset (bf16)

    // staging coords
    const int krow = tid >> 4, kcol = (tid & 15) * 8;   // K: 16 rows/pass
    const int vrow = tid >> 3, vcol = (tid & 7) * 8;    // V: 32 rows/pass

    // ---- stage Q tile into Ks, extract per-wave B-frags (Q[q=fr][m]) ----
    #pragma unroll
    for (int pl = 0; pl < 2; ++pl) {
        const unsigned short* src = pl ? qi : qr;
        #pragma unroll
        for (int p = 0; p < 4; ++p)
            *(short8*)&Ks[pl][p * 16 + krow][kcol] =
                *(const short8*)&src[base_qk + (size_t)(q0 + p * 16 + krow) * M_DIM + kcol];
    }
    __syncthreads();
    short8 Bqr[4], Bqi[4];
    {
        const int qrow = wave * 16 + fr;
        #pragma unroll
        for (int ks = 0; ks < 4; ++ks) {
            Bqr[ks] = *(const short8*)&Ks[0][qrow][ks * 32 + fk];
            Bqi[ks] = *(const short8*)&Ks[1][qrow][ks * 32 + fk];
        }
    }

    f32x4 Ore[4], Oim[4];   // O^T[v = vt*16+fg*4+reg][q = fr]
    #pragma unroll
    for (int vt = 0; vt < 4; ++vt) {
        Ore[vt] = (f32x4){0.f, 0.f, 0.f, 0.f};
        Oim[vt] = (f32x4){0.f, 0.f, 0.f, 0.f};
    }
    float mrun = -INFINITY, lrun = 0.f;

    const float scale = 0.088388347648318447f;  // 1/sqrt(128)
    const int qglob = q0 + wave * 16 + fr;      // this lane's q

    // ---- prefetch tile t0=0 into registers ----
    short8 pk[2][4], pv[2][2];
    #pragma unroll
    for (int pl = 0; pl < 2; ++pl) {
        const unsigned short* src = pl ? ki : kr;
        #pragma unroll
        for (int p = 0; p < 4; ++p)
            pk[pl][p] = *(const short8*)&src[base_qk + (size_t)(p * 16 + krow) * M_DIM + kcol];
    }
    #pragma unroll
    for (int pl = 0; pl < 2; ++pl) {
        const unsigned short* src = pl ? vit : vrt;
        #pragma unroll
        for (int p = 0; p < 2; ++p)
            pv[pl][p] = *(const short8*)&src[base_v + (size_t)(p * 32 + vrow) * S_DIM + vcol];
    }

    for (int t0 = 0; t0 <= q0; t0 += 64) {
        __syncthreads();   // prior readers of Ks/Vs done (iter0: Q frags extracted)
        // ---- commit prefetched K/V tile to LDS ----
        #pragma unroll
        for (int pl = 0; pl < 2; ++pl) {
            #pragma unroll
            for (int p = 0; p < 4; ++p)
                *(short8*)&Ks[pl][p * 16 + krow][kcol] = pk[pl][p];
            #pragma unroll
            for (int p = 0; p < 2; ++p)
                *(short8*)&Vs[pl][p * 32 + vrow][vcol] = pv[pl][p];
        }
        __syncthreads();

        // ---- issue next tile's global loads (consumed next iteration) ----
        if (t0 + 64 <= q0) {
            const int tn = t0 + 64;
            #pragma unroll
            for (int pl = 0; pl < 2; ++pl) {
                const unsigned short* src = pl ? ki : kr;
                #pragma unroll
                for (int p = 0; p < 4; ++p)
                    pk[pl][p] = *(const short8*)&src[base_qk + (size_t)(tn + p * 16 + krow) * M_DIM + kcol];
            }
            #pragma unroll
            for (int pl = 0; pl < 2; ++pl) {
                const unsigned short* src = pl ? vit : vrt;
                #pragma unroll
                for (int p = 0; p < 2; ++p)
                    pv[pl][p] = *(const short8*)&src[base_v + (size_t)(p * 32 + vrow) * S_DIM + tn + vcol];
            }
        }

        // ---- S^T = K Q^T (complex): A = K frags, B = Q frags ----
        f32x4 Sre[4], Sim[4];   // t = tt*16 + fg*4 + reg, q = fr
        __builtin_amdgcn_s_setprio(1);
        #pragma unroll
        for (int tt = 0; tt < 4; ++tt) {
            Sre[tt] = (f32x4){0.f, 0.f, 0.f, 0.f};
            Sim[tt] = (f32x4){0.f, 0.f, 0.f, 0.f};
            const int trow = tt * 16 + fr;
            #pragma unroll
            for (int ks = 0; ks < 4; ++ks) {
                const short8 Akr = *(const short8*)&Ks[0][trow][ks * 32 + fk];
                const short8 Aki = *(const short8*)&Ks[1][trow][ks * 32 + fk];
                int4v t = *(int4v*)&Aki;
                t = t ^ (int)0x80008000;       // -Ki (transient)
                const short8 Akin = *(short8*)&t;
                Sre[tt] = __builtin_amdgcn_mfma_f32_16x16x32_bf16(Akr,  Bqr[ks], Sre[tt], 0, 0, 0);
                Sre[tt] = __builtin_amdgcn_mfma_f32_16x16x32_bf16(Akin, Bqi[ks], Sre[tt], 0, 0, 0);
                Sim[tt] = __builtin_amdgcn_mfma_f32_16x16x32_bf16(Akr,  Bqi[ks], Sim[tt], 0, 0, 0);
                Sim[tt] = __builtin_amdgcn_mfma_f32_16x16x32_bf16(Aki,  Bqr[ks], Sim[tt], 0, 0, 0);
            }
        }
        __builtin_amdgcn_s_setprio(0);

        // ---- amplitude + causal mask; t-reduction in-lane + 2 quad shfls ----
        float amp[4][4];
        float rowmax = -INFINITY;
        #pragma unroll
        for (int tt = 0; tt < 4; ++tt) {
            #pragma unroll
            for (int r = 0; r < 4; ++r) {
                const int tg = t0 + tt * 16 + fg * 4 + r;
                const float re = Sre[tt][r], im = Sim[tt][r];
                const float a = sqrtf(re * re + im * im) * scale;
                const float av = (tg > qglob) ? -INFINITY : a;
                amp[tt][r] = av;
                rowmax = fmaxf(rowmax, av);
            }
        }
        rowmax = fmaxf(rowmax, __shfl_xor(rowmax, 16));
        rowmax = fmaxf(rowmax, __shfl_xor(rowmax, 32));
        const float nm = fmaxf(mrun, rowmax);
        const float alpha = __expf(mrun - nm);
        mrun = nm;
        float psum = 0.f;
        #pragma unroll
        for (int tt = 0; tt < 4; ++tt) {
            #pragma unroll
            for (int r = 0; r < 4; ++r) {
                const float p = __expf(amp[tt][r] - nm);
                psum += p;
                Ps[wave][fr][tt * 16 + fg * 4 + r] = f2bf(p);
            }
        }
        psum += __shfl_xor(psum, 16);
        psum += __shfl_xor(psum, 32);
        lrun = lrun * alpha + psum;

        #pragma unroll
        for (int vt = 0; vt < 4; ++vt)
            #pragma unroll
            for (int r = 0; r < 4; ++r) { Ore[vt][r] *= alpha; Oim[vt][r] *= alpha; }

        // ---- O^T += V^T P^T : A = V^T frags, B = P frags (per-wave LDS) ----
        const short8 Bp0 = *(const short8*)&Ps[wave][fr][fk];
        const short8 Bp1 = *(const short8*)&Ps[wave][fr][32 + fk];
        __builtin_amdgcn_s_setprio(1);
        #pragma unroll
        for (int vt = 0; vt < 4; ++vt) {
            const int vr2 = vt * 16 + fr;
            const short8 Ar0 = *(const short8*)&Vs[0][vr2][fk];
            const short8 Ar1 = *(const short8*)&Vs[0][vr2][32 + fk];
            const short8 Ai0 = *(const short8*)&Vs[1][vr2][fk];
            const short8 Ai1 = *(const short8*)&Vs[1][vr2][32 + fk];
            Ore[vt] = __builtin_amdgcn_mfma_f32_16x16x32_bf16(Ar0, Bp0, Ore[vt], 0, 0, 0);
            Ore[vt] = __builtin_amdgcn_mfma_f32_16x16x32_bf16(Ar1, Bp1, Ore[vt], 0, 0, 0);
            Oim[vt] = __builtin_amdgcn_mfma_f32_16x16x32_bf16(Ai0, Bp0, Oim[vt], 0, 0, 0);
            Oim[vt] = __builtin_amdgcn_mfma_f32_16x16x32_bf16(Ai1, Bp1, Oim[vt], 0, 0, 0);
        }
        __builtin_amdgcn_s_setprio(0);
    }

    // ---- epilogue: lane owns q = qglob; v = vt*16 + fg*4 + reg ----
    const int b = bh >> 4, h = bh & 15;
    const float inv = 1.0f / lrun;
    const size_t base = ((size_t)(qglob * B_DIM + b)) * E_DIM + h * V_DIM;
    #pragma unroll
    for (int vt = 0; vt < 4; ++vt) {
        ushort4 pr, pi;
        pr.x = f2bf(Ore[vt][0] * inv); pr.y = f2bf(Ore[vt][1] * inv);
        pr.z = f2bf(Ore[vt][2] * inv); pr.w = f2bf(Ore[vt][3] * inv);
        pi.x = f2bf(Oim[vt][0] * inv); pi.y = f2bf(Oim[vt][1] * inv);
        pi.z = f2bf(Oim[vt][2] * inv); pi.w = f2bf(Oim[vt][3] * inv);
        *(ushort4*)&updre[base + vt * 16 + fg * 4] = pr;
        *(ushort4*)&updim[base + vt * 16 + fg * 4] = pi;
    }
}

extern "C" void kernel_launch(void* const* d_in, const int* in_sizes, int n_in,
                              void* d_out, int out_size, void* d_ws, size_t ws_size,
                              hipStream_t stream) {
    const float* xre  = (const float*)d_in[0];
    const float* xim  = (const float*)d_in[1];
    const float* wqre = (const float*)d_in[2];
    const float* wqim = (const float*)d_in[3];
    const float* wkre = (const float*)d_in[4];
    const float* wkim = (const float*)d_in[5];
    const float* wvre = (const float*)d_in[6];
    const float* wvim = (const float*)d_in[7];
    const float* wore = (const float*)d_in[8];
    const float* woim = (const float*)d_in[9];
    float* out = (float*)d_out;

    // workspace layout (~160 MB)
    char* p = (char*)d_ws;
    const size_t QK = (size_t)B_DIM * H_DIM * S_DIM * M_DIM;   // 8.39M
    const size_t VS = (size_t)B_DIM * H_DIM * S_DIM * V_DIM;   // 4.19M
    const size_t SBE = (size_t)S_DIM * B_DIM * E_DIM;          // 4.19M
    unsigned short* qrw = (unsigned short*)p;  p += QK * 2;
    unsigned short* qiw = (unsigned short*)p;  p += QK * 2;
    unsigned short* krw = (unsigned short*)p;  p += QK * 2;
    unsigned short* kiw = (unsigned short*)p;  p += QK * 2;
    unsigned short* vrw = (unsigned short*)p;  p += VS * 2;
    unsigned short* viw = (unsigned short*)p;  p += VS * 2;
    unsigned short* vrt = (unsigned short*)p;  p += VS * 2;
    unsigned short* vit = (unsigned short*)p;  p += VS * 2;
    unsigned short* updre = (unsigned short*)p; p += SBE * 2;
    unsigned short* updim = (unsigned short*)p; p += SBE * 2;
    unsigned short* xbre  = (unsigned short*)p; p += SBE * 2;
    unsigned short* xbim  = (unsigned short*)p; p += SBE * 2;
    unsigned short* wbre  = (unsigned short*)p; p += (size_t)5120 * E_DIM * 2;
    unsigned short* wbim  = (unsigned short*)p; p += (size_t)5120 * E_DIM * 2;
    unsigned short* wtre  = (unsigned short*)p; p += (size_t)E_DIM * E_DIM * 2;
    unsigned short* wtim  = (unsigned short*)p; p += (size_t)E_DIM * E_DIM * 2;

    // bf16 conversion (single fused launch) + wo transpose
    convert_all<<<9216, 256, 0, stream>>>(xre, xim, wqre, wqim, wkre, wkim, wvre, wvim,
                                          xbre, xbim, wbre, wbim);
    transpose_wo<<<dim3(32, 32), 256, 0, stream>>>(wore, woim, wtre, wtim);

    // QKV projection (bf16 MFMA 32x32x16, T3-min double-buffer) -> separated planes
    cgemm<0><<<dim3(32, 40), 256, 0, stream>>>(xbre, xbim, wbre, wbim,
                                               qrw, qiw, krw, kiw, vrw, viw,
                                               nullptr, nullptr, nullptr);
    // V -> V^T planes
    vtrans<<<dim3(16, 64), 256, 0, stream>>>(vrw, viw, vrt, vit);
    // MFMA flash attention (S^T orientation)
    attn_mfma<<<dim3(16, 64), 256, 0, stream>>>(qrw, qiw, krw, kiw, vrt, vit, updre, updim);
    // output projection + residual (plain stores)
    cgemm<1><<<dim3(32, 8), 256, 0, stream>>>(updre, updim, wtre, wtim,
                                              nullptr, nullptr, nullptr, nullptr, nullptr, nullptr,
                                              xre, xim, out);
}

// Round 5
// 453.814 us; speedup vs baseline: 1.0890x; 1.0890x over previous
//
#include <hip/hip_runtime.h>
#include <math.h>

#define S_DIM 1024
#define B_DIM 4
#define E_DIM 1024
#define H_DIM 16
#define M_DIM 128
#define V_DIM 64

typedef __attribute__((ext_vector_type(8))) short short8;
typedef __attribute__((ext_vector_type(4))) float f32x4;
typedef __attribute__((ext_vector_type(4))) int int4v;

__device__ __forceinline__ unsigned short f2bf(float f) {
    union { float f; unsigned u; } v; v.f = f;
    unsigned r = v.u + 0x7FFFu + ((v.u >> 16) & 1u);   // round-to-nearest-even
    return (unsigned short)(r >> 16);
}

__device__ __forceinline__ void async16(const unsigned short* g, unsigned short* l) {
    __builtin_amdgcn_global_load_lds(
        (const __attribute__((address_space(1))) void*)g,
        (__attribute__((address_space(3))) void*)l,
        16, 0, 0);
}

// ---------------- convert: fp32 (re,im) -> bf16, all 4 tensors in one launch ----------------
// segments (in float4 units): x 1048576 | wq 524288 | wk 524288 | wv 262144
__global__ __launch_bounds__(256) void convert_all(
    const float* __restrict__ xre,  const float* __restrict__ xim,
    const float* __restrict__ wqre, const float* __restrict__ wqim,
    const float* __restrict__ wkre, const float* __restrict__ wkim,
    const float* __restrict__ wvre, const float* __restrict__ wvim,
    unsigned short* __restrict__ xbre, unsigned short* __restrict__ xbim,
    unsigned short* __restrict__ wbre, unsigned short* __restrict__ wbim)
{
    const int i = blockIdx.x * 256 + threadIdx.x;
    const float *re, *im;
    unsigned short *dr, *di;
    int j;
    if (i < 1048576)      { re = xre;  im = xim;  dr = xbre;               di = xbim;               j = i; }
    else if (i < 1572864) { re = wqre; im = wqim; dr = wbre;               di = wbim;               j = i - 1048576; }
    else if (i < 2097152) { re = wkre; im = wkim; dr = wbre + 2048 * 1024; di = wbim + 2048 * 1024; j = i - 1572864; }
    else                  { re = wvre; im = wvim; dr = wbre + 4096 * 1024; di = wbim + 4096 * 1024; j = i - 2097152; }
    float4 r = ((const float4*)re)[j];
    float4 m = ((const float4*)im)[j];
    ushort4 ro, mo;
    ro.x = f2bf(r.x); ro.y = f2bf(r.y); ro.z = f2bf(r.z); ro.w = f2bf(r.w);
    mo.x = f2bf(m.x); mo.y = f2bf(m.y); mo.z = f2bf(m.z); mo.w = f2bf(m.w);
    ((ushort4*)dr)[j] = ro;
    ((ushort4*)di)[j] = mo;
}

// wo (e,f) -> woT (f,e) bf16
__global__ __launch_bounds__(256) void transpose_wo(
    const float* __restrict__ wore, const float* __restrict__ woim,
    unsigned short* __restrict__ wtre, unsigned short* __restrict__ wtim)
{
    __shared__ float tr[32][33], ti[32][33];
    const int bx = blockIdx.x * 32;   // e range
    const int by = blockIdx.y * 32;   // f range
    const int tx = threadIdx.x & 31, ty = threadIdx.x >> 5;
    for (int i = ty; i < 32; i += 8) {
        tr[i][tx] = wore[(bx + i) * E_DIM + by + tx];
        ti[i][tx] = woim[(bx + i) * E_DIM + by + tx];
    }
    __syncthreads();
    for (int i = ty; i < 32; i += 8) {
        wtre[(by + i) * E_DIM + bx + tx] = f2bf(tr[tx][i]);
        wtim[(by + i) * E_DIM + bx + tx] = f2bf(ti[tx][i]);
    }
}

// v planes [bh][t][64] -> v^T planes [bh][v][1024]
__global__ __launch_bounds__(256) void vtrans(
    const unsigned short* __restrict__ vrp, const unsigned short* __restrict__ vip,
    unsigned short* __restrict__ vrt, unsigned short* __restrict__ vit)
{
    __shared__ unsigned short tl[2][64][66];
    const int tid = threadIdx.x;
    const int t0 = blockIdx.x * 64;
    const int bh = blockIdx.y;
    #pragma unroll
    for (int pl = 0; pl < 2; ++pl) {
        const unsigned short* src = pl ? vip : vrp;
        #pragma unroll
        for (int p = 0; p < 2; ++p) {
            const int row = p * 32 + (tid >> 3);
            const int col = (tid & 7) * 8;
            short8 d = *(const short8*)&src[((size_t)bh * S_DIM + t0 + row) * V_DIM + col];
            #pragma unroll
            for (int j = 0; j < 8; ++j) tl[pl][row][col + j] = (unsigned short)d[j];
        }
    }
    __syncthreads();
    #pragma unroll
    for (int pl = 0; pl < 2; ++pl) {
        unsigned short* dst = pl ? vit : vrt;
        #pragma unroll
        for (int p = 0; p < 2; ++p) {
            const int v = p * 32 + (tid >> 3);
            const int tc = (tid & 7) * 8;
            short8 d;
            #pragma unroll
            for (int j = 0; j < 8; ++j) d[j] = (short)tl[pl][tc + j][v];
            *(short8*)&dst[((size_t)bh * V_DIM + v) * S_DIM + t0 + tc] = d;
        }
    }
}

// ---------------- complex bf16 MFMA GEMM: C = A * B^T ----------------
// Round-4 post-mortem: 32x32x16 frags reintroduced 8-way bank conflicts
// (1.05e7) — the chunk-XOR swizzle is only conflict-free for the 16-row x
// 4-quad read pattern. Round-5: keep the VERIFIED 16x16x32 read pattern
// (zero conflicts in rounds 2-3) and raise FLOP per LDS byte via a larger
// wave tile instead: block 128x128, 4 waves (2x2), wave tile 64x64 ->
// 16 ds_read_b128 -> 64 MFMA per wave-slice (4.0 MFMA/read vs 2.67).
// Per-CU arithmetic: LDS ~50 us < MFMA ~83 us -> LDS leaves critical path.
// T3-min double-buffer (2 x 32 KB = 64 KB LDS -> 2 blocks/CU): next slice's
// global_load_lds issued BEFORE current slice's ds_read+MFMA; vmcnt(0)
// drained AFTER the MFMA cluster; one barrier per slice.
// Chunk-XOR swizzle: physical 16B chunk = logical ^ ((row>>1)&3);
// pre-swizzled GLOBAL source col (gload_lds dest linear) + same XOR on read.
// MODE 0: Mr=4096 (s,b), Nc=5120 (q|k|v) -> bf16 planes qr/qi/kr/ki/vr/vi
// MODE 1: Mr=4096, Nc=1024 -> out = acc + x (fp32, stacked re/im), plain stores
template<int MODE>
__global__ __launch_bounds__(256, 2) void cgemm(
    const unsigned short* __restrict__ Are, const unsigned short* __restrict__ Aim,
    const unsigned short* __restrict__ Bre, const unsigned short* __restrict__ Bim,
    unsigned short* __restrict__ qrp, unsigned short* __restrict__ qip,
    unsigned short* __restrict__ krp, unsigned short* __restrict__ kip,
    unsigned short* __restrict__ vrp, unsigned short* __restrict__ vip,
    const float* __restrict__ xre, const float* __restrict__ xim,
    float* __restrict__ out)
{
    // 64 KB: 2 slice buffers x (Ar[128][32] | Ai[128][32] | Br[128][32] | Bi[128][32])
    __shared__ __align__(16) unsigned short lds[32768];
    const int tid  = threadIdx.x;
    const int wave = tid >> 6;
    const int lane = tid & 63;
    const int r0 = blockIdx.x * 128;   // m fastest: consecutive blocks share B panel
    const int j0 = blockIdx.y * 128;
    const int wm = (wave >> 1) * 64;   // m half
    const int wn = (wave & 1) * 64;    // n half

    f32x4 accre[4][4], accim[4][4];
    #pragma unroll
    for (int i = 0; i < 4; ++i)
        #pragma unroll
        for (int j = 0; j < 4; ++j) {
            accre[i][j] = (f32x4){0.f, 0.f, 0.f, 0.f};
            accim[i][j] = (f32x4){0.f, 0.f, 0.f, 0.f};
        }

    // staging (round-4 verified-linear): thread t covers rows sr=t>>2 and
    // sr+64 of each plane, physical 16B chunk t&3. Physical chunk holds
    // logical chunk (t&3)^((row>>1)&3); gload_lds dest stays linear, so the
    // XOR is applied to the GLOBAL source column. (row>>1)&3 is identical
    // for rows sr and sr+64, so one scol serves both.
    const int sr   = tid >> 2;
    const int sc   = (tid & 3) * 8;                          // physical chunk (shorts)
    const int scol = ((tid & 3) ^ ((tid >> 3) & 3)) * 8;     // pre-swizzled source col

    // fragment reads (rounds 2-3 verified zero-conflict pattern):
    const int fr = lane & 15;                                // frag m/n index
    const int xc = ((lane >> 4) ^ ((lane >> 1) & 3)) * 8;    // swizzled k-chunk on read

    #define STAGE(sl, bb) { \
        const int kg = (sl) * 32; \
        unsigned short* b_ = &lds[(bb) * 16384]; \
        const size_t ga0 = (size_t)(r0 + sr) * E_DIM + kg + scol; \
        const size_t ga1 = (size_t)(r0 + 64 + sr) * E_DIM + kg + scol; \
        const size_t gb0 = (size_t)(j0 + sr) * E_DIM + kg + scol; \
        const size_t gb1 = (size_t)(j0 + 64 + sr) * E_DIM + kg + scol; \
        async16(Are + ga0, b_ + sr * 32 + sc); \
        async16(Are + ga1, b_ + (64 + sr) * 32 + sc); \
        async16(Aim + ga0, b_ + 4096 + sr * 32 + sc); \
        async16(Aim + ga1, b_ + 4096 + (64 + sr) * 32 + sc); \
        async16(Bre + gb0, b_ + 8192 + sr * 32 + sc); \
        async16(Bre + gb1, b_ + 8192 + (64 + sr) * 32 + sc); \
        async16(Bim + gb0, b_ + 12288 + sr * 32 + sc); \
        async16(Bim + gb1, b_ + 12288 + (64 + sr) * 32 + sc); }

    // prologue: slice 0 -> buf0, drain, barrier
    STAGE(0, 0)
    asm volatile("s_waitcnt vmcnt(0)" ::: "memory");
    __builtin_amdgcn_s_barrier();

    #pragma unroll 1
    for (int s = 0; s < 32; ++s) {
        // issue next slice's loads first (fly during ds_read + MFMA below)
        if (s < 31) STAGE(s + 1, (s + 1) & 1)

        const unsigned short* buf = &lds[(s & 1) * 16384];
        short8 ar[4], ai[4];
        #pragma unroll
        for (int im = 0; im < 4; ++im) {
            const int ro = (wm + im * 16 + fr) * 32 + xc;
            ar[im] = *(const short8*)&buf[ro];
            ai[im] = *(const short8*)&buf[4096 + ro];
        }
        #pragma unroll
        for (int jn = 0; jn < 4; ++jn) {
            const int ro = (wn + jn * 16 + fr) * 32 + xc;
            const short8 br = *(const short8*)&buf[8192 + ro];
            const short8 bi = *(const short8*)&buf[12288 + ro];
            int4v t = *(int4v*)&bi;
            t = t ^ (int)0x80008000;       // bin = -bi (transient)
            const short8 bin = *(short8*)&t;
            #pragma unroll
            for (int im = 0; im < 4; ++im) {
                accre[im][jn] = __builtin_amdgcn_mfma_f32_16x16x32_bf16(ar[im], br,  accre[im][jn], 0, 0, 0);
                accre[im][jn] = __builtin_amdgcn_mfma_f32_16x16x32_bf16(ai[im], bin, accre[im][jn], 0, 0, 0);
                accim[im][jn] = __builtin_amdgcn_mfma_f32_16x16x32_bf16(ar[im], bi,  accim[im][jn], 0, 0, 0);
                accim[im][jn] = __builtin_amdgcn_mfma_f32_16x16x32_bf16(ai[im], br,  accim[im][jn], 0, 0, 0);
            }
        }

        if (s < 31) {
            // next slice fully landed (loads had the whole MFMA cluster to fly);
            // all waves' ds_reads of buf[s&1] retired (consumed by MFMA) ->
            // after this barrier buf[s&1] is safe to overwrite at s+1.
            asm volatile("s_waitcnt vmcnt(0)" ::: "memory");
            __builtin_amdgcn_s_barrier();
        }
    }
    #undef STAGE

    // epilogue: D row = (lane>>4)*4+reg, col = lane&15  [measured m89/m91]
    #pragma unroll
    for (int im = 0; im < 4; ++im) {
        #pragma unroll
        for (int reg = 0; reg < 4; ++reg) {
            const int r = r0 + wm + im * 16 + (lane >> 4) * 4 + reg;
            #pragma unroll
            for (int jn = 0; jn < 4; ++jn) {
                const int j = j0 + wn + jn * 16 + fr;
                const float vr = accre[im][jn][reg];
                const float vi = accim[im][jn][reg];
                if (MODE == 0) {
                    const int s = r >> 2, b = r & 3;   // r = s*B + b
                    if (j < 2048) {
                        const int h = j >> 7, m = j & 127;
                        const size_t off = ((size_t)(b * H_DIM + h) * S_DIM + s) * M_DIM + m;
                        qrp[off] = f2bf(vr); qip[off] = f2bf(vi);
                    } else if (j < 4096) {
                        const int jl = j - 2048, h = jl >> 7, m = jl & 127;
                        const size_t off = ((size_t)(b * H_DIM + h) * S_DIM + s) * M_DIM + m;
                        krp[off] = f2bf(vr); kip[off] = f2bf(vi);
                    } else {
                        const int jl = j - 4096, h = jl >> 6, vv = jl & 63;
                        const size_t off = ((size_t)(b * H_DIM + h) * S_DIM + s) * V_DIM + vv;
                        vrp[off] = f2bf(vr); vip[off] = f2bf(vi);
                    }
                } else {
                    const int idx = r * E_DIM + j;
                    out[idx] = vr + xre[idx];
                    out[S_DIM * B_DIM * E_DIM + idx] = vi + xim[idx];
                }
            }
        }
    }
}

// ---------------- K2: MFMA flash attention, S^T orientation ----------------
// block = one (b,h) x 64 q; 4 waves x 16 q-cols; K-tile 64.
// S^T = K*Q^T: C col = q = lane&15 -> t-reduction is in-lane + 2 quad shfls;
// m/l/alpha are per-lane scalars. O accumulates as O^T[v][q] (col=q).
// setprio(1) around MFMA clusters (T5: +4-7% on attn, m191).
__global__ __launch_bounds__(256, 2) void attn_mfma(
    const unsigned short* __restrict__ qr, const unsigned short* __restrict__ qi,
    const unsigned short* __restrict__ kr, const unsigned short* __restrict__ ki,
    const unsigned short* __restrict__ vrt, const unsigned short* __restrict__ vit,
    unsigned short* __restrict__ updre, unsigned short* __restrict__ updim)
{
    __shared__ __align__(16) unsigned short Ks[2][64][136];  // K tile [plane][t][m] (Q staged here first)
    __shared__ __align__(16) unsigned short Vs[2][64][72];   // V^T tile [plane][v][t]
    __shared__ __align__(16) unsigned short Ps[4][16][80];   // per-wave P [q][t], pitch 80: 2-way banks

    const int tid  = threadIdx.x;
    const int wave = tid >> 6;
    const int lane = tid & 63;
    const int qt = (int)gridDim.x - 1 - blockIdx.x;  // long blocks launch first
    const int bh = blockIdx.y;
    const int q0 = qt * 64;
    const size_t base_qk = (size_t)bh * S_DIM * M_DIM;
    const size_t base_v  = (size_t)bh * V_DIM * S_DIM;

    const int fr = lane & 15;        // q col (QK/PV); A-frag row index
    const int fg = lane >> 4;        // quad 0..3
    const int fk = fg * 8;           // frag k offset (bf16)

    // staging coords
    const int krow = tid >> 4, kcol = (tid & 15) * 8;   // K: 16 rows/pass
    const int vrow = tid >> 3, vcol = (tid & 7) * 8;    // V: 32 rows/pass

    // ---- stage Q tile into Ks, extract per-wave B-frags (Q[q=fr][m]) ----
    #pragma unroll
    for (int pl = 0; pl < 2; ++pl) {
        const unsigned short* src = pl ? qi : qr;
        #pragma unroll
        for (int p = 0; p < 4; ++p)
            *(short8*)&Ks[pl][p * 16 + krow][kcol] =
                *(const short8*)&src[base_qk + (size_t)(q0 + p * 16 + krow) * M_DIM + kcol];
    }
    __syncthreads();
    short8 Bqr[4], Bqi[4];
    {
        const int qrow = wave * 16 + fr;
        #pragma unroll
        for (int ks = 0; ks < 4; ++ks) {
            Bqr[ks] = *(const short8*)&Ks[0][qrow][ks * 32 + fk];
            Bqi[ks] = *(const short8*)&Ks[1][qrow][ks * 32 + fk];
        }
    }

    f32x4 Ore[4], Oim[4];   // O^T[v = vt*16+fg*4+reg][q = fr]
    #pragma unroll
    for (int vt = 0; vt < 4; ++vt) {
        Ore[vt] = (f32x4){0.f, 0.f, 0.f, 0.f};
        Oim[vt] = (f32x4){0.f, 0.f, 0.f, 0.f};
    }
    float mrun = -INFINITY, lrun = 0.f;

    const float scale = 0.088388347648318447f;  // 1/sqrt(128)
    const int qglob = q0 + wave * 16 + fr;      // this lane's q

    // ---- prefetch tile t0=0 into registers ----
    short8 pk[2][4], pv[2][2];
    #pragma unroll
    for (int pl = 0; pl < 2; ++pl) {
        const unsigned short* src = pl ? ki : kr;
        #pragma unroll
        for (int p = 0; p < 4; ++p)
            pk[pl][p] = *(const short8*)&src[base_qk + (size_t)(p * 16 + krow) * M_DIM + kcol];
    }
    #pragma unroll
    for (int pl = 0; pl < 2; ++pl) {
        const unsigned short* src = pl ? vit : vrt;
        #pragma unroll
        for (int p = 0; p < 2; ++p)
            pv[pl][p] = *(const short8*)&src[base_v + (size_t)(p * 32 + vrow) * S_DIM + vcol];
    }

    for (int t0 = 0; t0 <= q0; t0 += 64) {
        __syncthreads();   // prior readers of Ks/Vs done (iter0: Q frags extracted)
        // ---- commit prefetched K/V tile to LDS ----
        #pragma unroll
        for (int pl = 0; pl < 2; ++pl) {
            #pragma unroll
            for (int p = 0; p < 4; ++p)
                *(short8*)&Ks[pl][p * 16 + krow][kcol] = pk[pl][p];
            #pragma unroll
            for (int p = 0; p < 2; ++p)
                *(short8*)&Vs[pl][p * 32 + vrow][vcol] = pv[pl][p];
        }
        __syncthreads();

        // ---- issue next tile's global loads (consumed next iteration) ----
        if (t0 + 64 <= q0) {
            const int tn = t0 + 64;
            #pragma unroll
            for (int pl = 0; pl < 2; ++pl) {
                const unsigned short* src = pl ? ki : kr;
                #pragma unroll
                for (int p = 0; p < 4; ++p)
                    pk[pl][p] = *(const short8*)&src[base_qk + (size_t)(tn + p * 16 + krow) * M_DIM + kcol];
            }
            #pragma unroll
            for (int pl = 0; pl < 2; ++pl) {
                const unsigned short* src = pl ? vit : vrt;
                #pragma unroll
                for (int p = 0; p < 2; ++p)
                    pv[pl][p] = *(const short8*)&src[base_v + (size_t)(p * 32 + vrow) * S_DIM + tn + vcol];
            }
        }

        // ---- S^T = K Q^T (complex): A = K frags, B = Q frags ----
        f32x4 Sre[4], Sim[4];   // t = tt*16 + fg*4 + reg, q = fr
        __builtin_amdgcn_s_setprio(1);
        #pragma unroll
        for (int tt = 0; tt < 4; ++tt) {
            Sre[tt] = (f32x4){0.f, 0.f, 0.f, 0.f};
            Sim[tt] = (f32x4){0.f, 0.f, 0.f, 0.f};
            const int trow = tt * 16 + fr;
            #pragma unroll
            for (int ks = 0; ks < 4; ++ks) {
                const short8 Akr = *(const short8*)&Ks[0][trow][ks * 32 + fk];
                const short8 Aki = *(const short8*)&Ks[1][trow][ks * 32 + fk];
                int4v t = *(int4v*)&Aki;
                t = t ^ (int)0x80008000;       // -Ki (transient)
                const short8 Akin = *(short8*)&t;
                Sre[tt] = __builtin_amdgcn_mfma_f32_16x16x32_bf16(Akr,  Bqr[ks], Sre[tt], 0, 0, 0);
                Sre[tt] = __builtin_amdgcn_mfma_f32_16x16x32_bf16(Akin, Bqi[ks], Sre[tt], 0, 0, 0);
                Sim[tt] = __builtin_amdgcn_mfma_f32_16x16x32_bf16(Akr,  Bqi[ks], Sim[tt], 0, 0, 0);
                Sim[tt] = __builtin_amdgcn_mfma_f32_16x16x32_bf16(Aki,  Bqr[ks], Sim[tt], 0, 0, 0);
            }
        }
        __builtin_amdgcn_s_setprio(0);

        // ---- amplitude + causal mask; t-reduction in-lane + 2 quad shfls ----
        float amp[4][4];
        float rowmax = -INFINITY;
        #pragma unroll
        for (int tt = 0; tt < 4; ++tt) {
            #pragma unroll
            for (int r = 0; r < 4; ++r) {
                const int tg = t0 + tt * 16 + fg * 4 + r;
                const float re = Sre[tt][r], im = Sim[tt][r];
                const float a = sqrtf(re * re + im * im) * scale;
                const float av = (tg > qglob) ? -INFINITY : a;
                amp[tt][r] = av;
                rowmax = fmaxf(rowmax, av);
            }
        }
        rowmax = fmaxf(rowmax, __shfl_xor(rowmax, 16));
        rowmax = fmaxf(rowmax, __shfl_xor(rowmax, 32));
        const float nm = fmaxf(mrun, rowmax);
        const float alpha = __expf(mrun - nm);
        mrun = nm;
        float psum = 0.f;
        #pragma unroll
        for (int tt = 0; tt < 4; ++tt) {
            #pragma unroll
            for (int r = 0; r < 4; ++r) {
                const float p = __expf(amp[tt][r] - nm);
                psum += p;
                Ps[wave][fr][tt * 16 + fg * 4 + r] = f2bf(p);
            }
        }
        psum += __shfl_xor(psum, 16);
        psum += __shfl_xor(psum, 32);
        lrun = lrun * alpha + psum;

        #pragma unroll
        for (int vt = 0; vt < 4; ++vt)
            #pragma unroll
            for (int r = 0; r < 4; ++r) { Ore[vt][r] *= alpha; Oim[vt][r] *= alpha; }

        // ---- O^T += V^T P^T : A = V^T frags, B = P frags (per-wave LDS) ----
        const short8 Bp0 = *(const short8*)&Ps[wave][fr][fk];
        const short8 Bp1 = *(const short8*)&Ps[wave][fr][32 + fk];
        __builtin_amdgcn_s_setprio(1);
        #pragma unroll
        for (int vt = 0; vt < 4; ++vt) {
            const int vr2 = vt * 16 + fr;
            const short8 Ar0 = *(const short8*)&Vs[0][vr2][fk];
            const short8 Ar1 = *(const short8*)&Vs[0][vr2][32 + fk];
            const short8 Ai0 = *(const short8*)&Vs[1][vr2][fk];
            const short8 Ai1 = *(const short8*)&Vs[1][vr2][32 + fk];
            Ore[vt] = __builtin_amdgcn_mfma_f32_16x16x32_bf16(Ar0, Bp0, Ore[vt], 0, 0, 0);
            Ore[vt] = __builtin_amdgcn_mfma_f32_16x16x32_bf16(Ar1, Bp1, Ore[vt], 0, 0, 0);
            Oim[vt] = __builtin_amdgcn_mfma_f32_16x16x32_bf16(Ai0, Bp0, Oim[vt], 0, 0, 0);
            Oim[vt] = __builtin_amdgcn_mfma_f32_16x16x32_bf16(Ai1, Bp1, Oim[vt], 0, 0, 0);
        }
        __builtin_amdgcn_s_setprio(0);
    }

    // ---- epilogue: lane owns q = qglob; v = vt*16 + fg*4 + reg ----
    const int b = bh >> 4, h = bh & 15;
    const float inv = 1.0f / lrun;
    const size_t base = ((size_t)(qglob * B_DIM + b)) * E_DIM + h * V_DIM;
    #pragma unroll
    for (int vt = 0; vt < 4; ++vt) {
        ushort4 pr, pi;
        pr.x = f2bf(Ore[vt][0] * inv); pr.y = f2bf(Ore[vt][1] * inv);
        pr.z = f2bf(Ore[vt][2] * inv); pr.w = f2bf(Ore[vt][3] * inv);
        pi.x = f2bf(Oim[vt][0] * inv); pi.y = f2bf(Oim[vt][1] * inv);
        pi.z = f2bf(Oim[vt][2] * inv); pi.w = f2bf(Oim[vt][3] * inv);
        *(ushort4*)&updre[base + vt * 16 + fg * 4] = pr;
        *(ushort4*)&updim[base + vt * 16 + fg * 4] = pi;
    }
}

extern "C" void kernel_launch(void* const* d_in, const int* in_sizes, int n_in,
                              void* d_out, int out_size, void* d_ws, size_t ws_size,
                              hipStream_t stream) {
    const float* xre  = (const float*)d_in[0];
    const float* xim  = (const float*)d_in[1];
    const float* wqre = (const float*)d_in[2];
    const float* wqim = (const float*)d_in[3];
    const float* wkre = (const float*)d_in[4];
    const float* wkim = (const float*)d_in[5];
    const float* wvre = (const float*)d_in[6];
    const float* wvim = (const float*)d_in[7];
    const float* wore = (const float*)d_in[8];
    const float* woim = (const float*)d_in[9];
    float* out = (float*)d_out;

    // workspace layout (~160 MB)
    char* p = (char*)d_ws;
    const size_t QK = (size_t)B_DIM * H_DIM * S_DIM * M_DIM;   // 8.39M
    const size_t VS = (size_t)B_DIM * H_DIM * S_DIM * V_DIM;   // 4.19M
    const size_t SBE = (size_t)S_DIM * B_DIM * E_DIM;          // 4.19M
    unsigned short* qrw = (unsigned short*)p;  p += QK * 2;
    unsigned short* qiw = (unsigned short*)p;  p += QK * 2;
    unsigned short* krw = (unsigned short*)p;  p += QK * 2;
    unsigned short* kiw = (unsigned short*)p;  p += QK * 2;
    unsigned short* vrw = (unsigned short*)p;  p += VS * 2;
    unsigned short* viw = (unsigned short*)p;  p += VS * 2;
    unsigned short* vrt = (unsigned short*)p;  p += VS * 2;
    unsigned short* vit = (unsigned short*)p;  p += VS * 2;
    unsigned short* updre = (unsigned short*)p; p += SBE * 2;
    unsigned short* updim = (unsigned short*)p; p += SBE * 2;
    unsigned short* xbre  = (unsigned short*)p; p += SBE * 2;
    unsigned short* xbim  = (unsigned short*)p; p += SBE * 2;
    unsigned short* wbre  = (unsigned short*)p; p += (size_t)5120 * E_DIM * 2;
    unsigned short* wbim  = (unsigned short*)p; p += (size_t)5120 * E_DIM * 2;
    unsigned short* wtre  = (unsigned short*)p; p += (size_t)E_DIM * E_DIM * 2;
    unsigned short* wtim  = (unsigned short*)p; p += (size_t)E_DIM * E_DIM * 2;

    // bf16 conversion (single fused launch) + wo transpose
    convert_all<<<9216, 256, 0, stream>>>(xre, xim, wqre, wqim, wkre, wkim, wvre, wvim,
                                          xbre, xbim, wbre, wbim);
    transpose_wo<<<dim3(32, 32), 256, 0, stream>>>(wore, woim, wtre, wtim);

    // QKV projection (bf16 MFMA 16x16x32, 64x64 wave tile, T3-min dbuf)
    cgemm<0><<<dim3(32, 40), 256, 0, stream>>>(xbre, xbim, wbre, wbim,
                                               qrw, qiw, krw, kiw, vrw, viw,
                                               nullptr, nullptr, nullptr);
    // V -> V^T planes
    vtrans<<<dim3(16, 64), 256, 0, stream>>>(vrw, viw, vrt, vit);
    // MFMA flash attention (S^T orientation)
    attn_mfma<<<dim3(16, 64), 256, 0, stream>>>(qrw, qiw, krw, kiw, vrt, vit, updre, updim);
    // output projection + residual (plain stores)
    cgemm<1><<<dim3(32, 8), 256, 0, stream>>>(updre, updim, wtre, wtim,
                                              nullptr, nullptr, nullptr, nullptr, nullptr, nullptr,
                                              xre, xim, out);
}